// Round 10
// baseline (224.424 us; speedup 1.0000x reference)
//
#include <hip/hip_runtime.h>
#include <hip/hip_fp16.h>
#include <float.h>

#define NC 64     // clusters
#define FD 128    // feature dim
#define LSTR 136  // LDS row stride in halfs (pad 16B; frag-read conflicts 2-way = free)

typedef _Float16 f16x8 __attribute__((ext_vector_type(8)));
typedef float f32x4 __attribute__((ext_vector_type(4)));

// ---------------- prep: fp16 cast, |x|^2, Mt build, S/done/out zero ----------------
__global__ void prep_kernel(const float* __restrict__ feat,
                            const int* __restrict__ labels,
                            float* __restrict__ sq,
                            unsigned short* __restrict__ Xh,
                            unsigned short* __restrict__ Mt,
                            float* __restrict__ S,
                            int* __restrict__ done,
                            float* __restrict__ out, int out_size,
                            int zeroS, int N) {
  int t = threadIdx.x;
  int row = blockIdx.x * 32 + (t >> 3);
  int o = t & 7;
  if (row < N) {
    const float* rp = feat + (size_t)row * FD;
    float s = 0.f;
#pragma unroll
    for (int j = 0; j < 4; ++j) {
      int c4 = o + 8 * j;
      float4 v = *(const float4*)(rp + c4 * 4);
      ushort4 h;
      h.x = __half_as_ushort(__float2half(v.x));   // RNE
      h.y = __half_as_ushort(__float2half(v.y));
      h.z = __half_as_ushort(__float2half(v.z));
      h.w = __half_as_ushort(__float2half(v.w));
      *(ushort4*)&Xh[(size_t)row * FD + c4 * 4] = h;
      s = fmaf(v.x, v.x, s); s = fmaf(v.y, v.y, s);
      s = fmaf(v.z, v.z, s); s = fmaf(v.w, v.w, s);
    }
    s += __shfl_xor(s, 1); s += __shfl_xor(s, 2); s += __shfl_xor(s, 4);
    if (o == 0) sq[row] = s;
  }
  // fallback mode only: zero the single-S accumulator
  if (zeroS && (blockIdx.x + 1) * 32 <= N) {
    float4 z = {0.f, 0.f, 0.f, 0.f};
    size_t base = (size_t)blockIdx.x * 32 * NC + t * 8;
    *(float4*)&S[base] = z;
    *(float4*)&S[base + 4] = z;
  }
  if (blockIdx.x == 0) {
    if (t < N / 128) done[t] = 0;
    if (t < out_size) out[t] = 0.f;
  }
  // build Mt[n][col] = (labels[col]==n) ? 1.0h : 0  (8-col chunks)
  {
    int chunksPerN = N >> 3;
    int total = NC * chunksPerN;
    for (int id = blockIdx.x * 256 + t; id < total; id += gridDim.x * 256) {
      int n = id / chunksPerN;
      int c0 = (id - n * chunksPerN) * 8;
      ushort4 lo, hi;
      lo.x = (labels[c0 + 0] == n) ? 0x3C00 : 0;
      lo.y = (labels[c0 + 1] == n) ? 0x3C00 : 0;
      lo.z = (labels[c0 + 2] == n) ? 0x3C00 : 0;
      lo.w = (labels[c0 + 3] == n) ? 0x3C00 : 0;
      hi.x = (labels[c0 + 4] == n) ? 0x3C00 : 0;
      hi.y = (labels[c0 + 5] == n) ? 0x3C00 : 0;
      hi.z = (labels[c0 + 6] == n) ? 0x3C00 : 0;
      hi.w = (labels[c0 + 7] == n) ? 0x3C00 : 0;
      *(ushort4*)&Mt[(size_t)n * N + c0] = lo;
      *(ushort4*)&Mt[(size_t)n * N + c0 + 4] = hi;
    }
  }
}

// ---------------- main: fp16 MFMA Gram + MFMA segment-sum (+ fused scoring) --------
// FUSED=true: each (rowGroup, by) block stores its partial S into its OWN slice
// S[by][N][NC] with plain agent-scope atomic stores (no RMW, disjoint, 64B-line
// covered). Last finisher per rowGroup (done-counter, acq_rel) sums slices into
// LDS and scores -- no global atomic RMW anywhere in the hot path.
// FUSED=false (ws fallback): r7 structure -- atomicAdd into single S; separate
// score kernel.
template <bool FUSED>
__global__ __launch_bounds__(256, 2)
void mfma_tile_kernel(const unsigned short* __restrict__ Xh,
                      const float* __restrict__ sq,
                      const unsigned short* __restrict__ Mt,
                      const int* __restrict__ labels,
                      float* __restrict__ S,
                      int* __restrict__ done,
                      float* __restrict__ out,
                      int N, int colsPerSplit) {
  __shared__ __align__(16) unsigned short Ah[128 * LSTR];  // 34816 B
  __shared__ __align__(16) unsigned short Bh[128 * LSTR];  // 34816 B, reused as D
  __shared__ int lastFlag;

  const int t = threadIdx.x;
  const int R = blockIdx.x * 128;
  const int cBeg = blockIdx.y * colsPerSplit;
  const int wave = t >> 6, lane = t & 63;
  const int mm = lane & 15, quad = lane >> 4;
  const int wr = wave >> 1, wc = wave & 1;   // 2x2 wave grid

  // stage A full-K: 2048 x 16B chunks over 256 threads
  const int sr = t >> 4, sk0 = (t & 15) * 8;
#pragma unroll
  for (int it = 0; it < 8; ++it)
    *(uint4*)&Ah[(sr + it * 16) * LSTR + sk0] =
        *(const uint4*)&Xh[(size_t)(R + sr + it * 16) * FD + sk0];

  // initial B prefetch (col-tile 0) into registers
  uint4 bpref[8];
#pragma unroll
  for (int it = 0; it < 8; ++it)
    bpref[it] = *(const uint4*)&Xh[(size_t)(cBeg + sr + it * 16) * FD + sk0];

  float sqi_r[4];
#pragma unroll
  for (int ib = 0; ib < 4; ++ib)
    sqi_r[ib] = sq[R + wr * 64 + ib * 16 + mm];

  f32x4 sacc[2][4];
#pragma unroll
  for (int rt = 0; rt < 2; ++rt)
#pragma unroll
    for (int lt = 0; lt < 4; ++lt) sacc[rt][lt] = (f32x4)0.f;

  const int numTiles = colsPerSplit / 128;
  for (int ct = 0; ct < numTiles; ++ct) {
    const int C0 = cBeg + ct * 128;
    __syncthreads();                         // prev S-pass done before Bh overwrite
#pragma unroll
    for (int it = 0; it < 8; ++it)
      *(uint4*)&Bh[(sr + it * 16) * LSTR + sk0] = bpref[it];
    const int nC0 = (ct + 1 < numTiles) ? C0 + 128 : cBeg;
#pragma unroll
    for (int it = 0; it < 8; ++it)
      bpref[it] = *(const uint4*)&Xh[(size_t)(nC0 + sr + it * 16) * FD + sk0];
    float sjr[4][4];
#pragma unroll
    for (int jb = 0; jb < 4; ++jb)
#pragma unroll
      for (int r = 0; r < 4; ++r)
        sjr[jb][r] = sq[C0 + wc * 64 + jb * 16 + quad * 4 + r];
    __syncthreads();                         // Bh ready

    // Dist pass: operands swapped -> transposed C/D fragments
    f32x4 dacc[4][4];
#pragma unroll
    for (int ib = 0; ib < 4; ++ib)
#pragma unroll
      for (int jb = 0; jb < 4; ++jb) dacc[ib][jb] = (f32x4)0.f;

#pragma unroll
    for (int ks = 0; ks < 4; ++ks) {
      const int ko = ks * 32 + quad * 8;
      f16x8 af[4], bf[4];
#pragma unroll
      for (int ib = 0; ib < 4; ++ib)
        af[ib] = *(const f16x8*)&Ah[(wr * 64 + ib * 16 + mm) * LSTR + ko];
#pragma unroll
      for (int jb = 0; jb < 4; ++jb)
        bf[jb] = *(const f16x8*)&Bh[(wc * 64 + jb * 16 + mm) * LSTR + ko];
#pragma unroll
      for (int ib = 0; ib < 4; ++ib)
#pragma unroll
        for (int jb = 0; jb < 4; ++jb)
          dacc[ib][jb] = __builtin_amdgcn_mfma_f32_16x16x32_f16(bf[jb], af[ib], dacc[ib][jb], 0, 0, 0);
    }
    __syncthreads();                         // all waves done reading Bh -> reuse as D

    // epilogue: lane holds row (lane&15), 4 contiguous cols (quad*4+r)
    const bool hasDiag = (R == C0);
#pragma unroll
    for (int ib = 0; ib < 4; ++ib) {
      const int rowLocal = wr * 64 + ib * 16 + mm;
      const float si = sqi_r[ib];
#pragma unroll
      for (int jb = 0; jb < 4; ++jb) {
        const int colBase = wc * 64 + jb * 16 + quad * 4;
        float d[4];
#pragma unroll
        for (int r = 0; r < 4; ++r) {
          float d2 = fmaf(-2.f, dacc[ib][jb][r], si + sjr[jb][r]);
          d[r] = __builtin_amdgcn_sqrtf(fmaxf(d2, 0.f));  // sqrt(0)=0: grad-safe
        }
        if (hasDiag) {
#pragma unroll
          for (int r = 0; r < 4; ++r)
            if (rowLocal == colBase + r) d[r] = 0.f;
        }
        uint2 pk;
        pk.x = __builtin_bit_cast(unsigned, __builtin_amdgcn_cvt_pkrtz(d[0], d[1]));
        pk.y = __builtin_bit_cast(unsigned, __builtin_amdgcn_cvt_pkrtz(d[2], d[3]));
        *(uint2*)&Bh[rowLocal * LSTR + colBase] = pk;    // 8B store, aligned
      }
    }

    // prefetch the 16 Mt frags; they complete inside the barrier's vmcnt drain
    f16x8 mbp[4][4];
#pragma unroll
    for (int ks = 0; ks < 4; ++ks)
#pragma unroll
      for (int lt = 0; lt < 4; ++lt)
        mbp[ks][lt] = *(const f16x8*)&Mt[(size_t)(lt * 16 + mm) * N + C0 + ks * 32 + quad * 8];
    __syncthreads();                         // D ready

    // S-pass: S_tile[128xNC] += D[128x128] x M[128xNC]
#pragma unroll
    for (int ks = 0; ks < 4; ++ks) {
      const int ko = ks * 32 + quad * 8;
      f16x8 da0 = *(const f16x8*)&Bh[(wave * 32 + mm) * LSTR + ko];
      f16x8 da1 = *(const f16x8*)&Bh[(wave * 32 + 16 + mm) * LSTR + ko];
#pragma unroll
      for (int lt = 0; lt < 4; ++lt) {
        sacc[0][lt] = __builtin_amdgcn_mfma_f32_16x16x32_f16(da0, mbp[ks][lt], sacc[0][lt], 0, 0, 0);
        sacc[1][lt] = __builtin_amdgcn_mfma_f32_16x16x32_f16(da1, mbp[ks][lt], sacc[1][lt], 0, 0, 0);
      }
    }
  }

  if (!FUSED) {
    // fallback: atomicAdd into single S; separate score kernel finishes
#pragma unroll
    for (int rt = 0; rt < 2; ++rt)
#pragma unroll
      for (int lt = 0; lt < 4; ++lt)
#pragma unroll
        for (int r = 0; r < 4; ++r) {
          int row = wave * 32 + rt * 16 + quad * 4 + r;
          atomicAdd(&S[(size_t)(R + row) * NC + lt * 16 + mm], sacc[rt][lt][r]);
        }
    return;
  }

  // -------- FUSED: plain agent-scope stores into this block's own slice --------
  // Slice blockIdx.y of S[colSplit][N][NC]; disjoint -> no RMW, no contention.
  // Per store inst: 4 quads x 16 consecutive cols = 4 fully-covered 64B lines.
#pragma unroll
  for (int rt = 0; rt < 2; ++rt)
#pragma unroll
    for (int lt = 0; lt < 4; ++lt)
#pragma unroll
      for (int r = 0; r < 4; ++r) {
        int row = wave * 32 + rt * 16 + quad * 4 + r;
        __hip_atomic_store(&S[((size_t)blockIdx.y * N + R + row) * NC + lt * 16 + mm],
                           sacc[rt][lt][r], __ATOMIC_RELAXED, __HIP_MEMORY_SCOPE_AGENT);
      }
  asm volatile("s_waitcnt vmcnt(0)" ::: "memory");   // stores complete
  __syncthreads();
  if (t == 0) {
    int old = __hip_atomic_fetch_add(&done[blockIdx.x], 1,
                                     __ATOMIC_ACQ_REL, __HIP_MEMORY_SCOPE_AGENT);
    lastFlag = (old == (int)gridDim.y - 1) ? 1 : 0;
  }
  __syncthreads();
  if (!lastFlag) return;

  // -------- last finisher: sum slices -> LDS (stride 65: conflict-free), score ----
  float* Sl = (float*)Ah;                    // 128*65*4 = 33280 B <= 34816
  int* hist = (int*)Bh;                      // 256 B
  float* red = (float*)Bh + NC;              // 1 KB
  if (t < NC) hist[t] = 0;
  __syncthreads();
  const int4* lab4 = (const int4*)labels;
  for (int i = t; i < N / 4; i += 256) {
    int4 v = lab4[i];
    atomicAdd(&hist[v.x], 1); atomicAdd(&hist[v.y], 1);
    atomicAdd(&hist[v.z], 1); atomicAdd(&hist[v.w], 1);
  }
  const int nSlices = (int)gridDim.y;
  for (int f = t; f < 128 * NC; f += 256) {  // coalesced agent loads per slice
    float s = 0.f;
    for (int sl = 0; sl < nSlices; ++sl)
      s += __hip_atomic_load(&S[((size_t)sl * N + R) * NC + f],
                             __ATOMIC_RELAXED, __HIP_MEMORY_SCOPE_AGENT);
    Sl[(f >> 6) * 65 + (f & 63)] = s;
  }
  __syncthreads();

  float score = 0.f;
  if (t < 128) {
    int li = labels[R + t];
    float own = (float)hist[li];
    float a = 0.f, b = FLT_MAX;
    const float* Si = &Sl[t * 65];
#pragma unroll
    for (int c = 0; c < NC; ++c) {
      float s = Si[c];
      float cf = (float)hist[c];
      if (c == li) a = s / fmaxf(own - 1.f, 1.f);
      else if (cf != 0.f) b = fminf(b, s / cf);
    }
    float mx = fmaxf(a, b);
    score = (own > 1.f) ? (b - a) / mx : 0.f;
  }
  red[t] = score;
  __syncthreads();
  for (int sft = 128; sft > 0; sft >>= 1) {
    if (t < sft) red[t] += red[t + sft];
    __syncthreads();
  }
  if (t == 0) atomicAdd(out, red[0] / (float)N);
}

// ---------------- fallback score kernel (r7) ----------------
__global__ void score_kernel(const float* __restrict__ S,
                             const int* __restrict__ labels,
                             float* __restrict__ out, int N) {
  __shared__ int hist[NC];
  __shared__ float red[128];
  int t = threadIdx.x;
  if (t < NC) hist[t] = 0;
  __syncthreads();
  const int4* lab4 = (const int4*)labels;
  for (int i = t; i < N / 4; i += 128) {
    int4 v = lab4[i];
    atomicAdd(&hist[v.x], 1); atomicAdd(&hist[v.y], 1);
    atomicAdd(&hist[v.z], 1); atomicAdd(&hist[v.w], 1);
  }
  __syncthreads();
  int i = blockIdx.x * 128 + t;
  float score = 0.f;
  if (i < N) {
    int li = labels[i];
    float own = (float)hist[li];
    float a = 0.f, b = FLT_MAX;
    const float* Si = S + (size_t)i * NC;
#pragma unroll
    for (int c = 0; c < NC; ++c) {
      float s = Si[c];
      float cf = (float)hist[c];
      if (c == li) a = s / fmaxf(own - 1.f, 1.f);
      else if (cf != 0.f) b = fminf(b, s / cf);
    }
    float mx = fmaxf(a, b);
    score = (own > 1.f) ? (b - a) / mx : 0.f;
  }
  red[t] = score;
  __syncthreads();
  for (int sft = 64; sft > 0; sft >>= 1) {
    if (t < sft) red[t] += red[t + sft];
    __syncthreads();
  }
  if (t == 0) atomicAdd(out, red[0] / (float)N);
}

extern "C" void kernel_launch(void* const* d_in, const int* in_sizes, int n_in,
                              void* d_out, int out_size, void* d_ws, size_t ws_size,
                              hipStream_t stream) {
  const float* feat = (const float*)d_in[0];
  const int* labels = (const int*)d_in[1];
  const int N = in_sizes[1];            // 8192; D=128, C=64 fixed by the reference
  float* out = (float*)d_out;
  char* ws = (char*)d_ws;
  const int colSplit = 8;               // 64 x 8 = 512 blocks = 2/CU (4 waves each)

  // ws: done(256B) | sq(N*4) | Xh(N*128*2) | Mt(64*N*2) | S...
  int*   done = (int*)ws;
  float* sq   = (float*)(ws + 256);
  size_t o = 256 + (size_t)N * 4;
  o = (o + 255) & ~(size_t)255;
  unsigned short* Xh = (unsigned short*)(ws + o);                       // N*FD*2
  unsigned short* Mt = (unsigned short*)(ws + o + (size_t)N * FD * 2);  // NC*N*2
  float* S = (float*)(ws + o + (size_t)N * FD * 2 + (size_t)NC * N * 2);
  size_t sBase = o + (size_t)N * FD * 2 + (size_t)NC * N * 2;
  size_t need_part = sBase + (size_t)colSplit * N * NC * 4;   // ~19.3 MB @8192
  bool fused = (ws_size >= need_part);

  prep_kernel<<<(N + 31) / 32, 256, 0, stream>>>(feat, labels, sq, Xh, Mt, S,
                                                 done, out, out_size,
                                                 fused ? 0 : 1, N);

  dim3 grid(N / 128, colSplit);
  if (fused) {
    mfma_tile_kernel<true><<<grid, 256, 0, stream>>>(Xh, sq, Mt, labels, S, done,
                                                     out, N, N / colSplit);
  } else {
    mfma_tile_kernel<false><<<grid, 256, 0, stream>>>(Xh, sq, Mt, labels, S, done,
                                                      out, N, N / colSplit);
    score_kernel<<<(N + 127) / 128, 128, 0, stream>>>(S, labels, out, N);
  }
}

// Round 11
// 176.247 us; speedup vs baseline: 1.2734x; 1.2734x over previous
//
#include <hip/hip_runtime.h>
#include <hip/hip_fp16.h>
#include <float.h>

#define NC 64     // clusters
#define FD 128    // feature dim
#define LSTR 136  // LDS row stride in halfs (pad 16B; frag-read conflicts 2-way = free)

typedef _Float16 f16x8 __attribute__((ext_vector_type(8)));
typedef float f32x4 __attribute__((ext_vector_type(4)));

// ---------------- prep: fp16 cast, |x|^2, Mt build, S/out zero ----------------
__global__ void prep_kernel(const float* __restrict__ feat,
                            const int* __restrict__ labels,
                            float* __restrict__ sq,
                            unsigned short* __restrict__ Xh,
                            unsigned short* __restrict__ Mt,
                            float* __restrict__ S,
                            float* __restrict__ out, int out_size, int N) {
  int t = threadIdx.x;
  int row = blockIdx.x * 32 + (t >> 3);
  int o = t & 7;
  if (row < N) {
    const float* rp = feat + (size_t)row * FD;
    float s = 0.f;
#pragma unroll
    for (int j = 0; j < 4; ++j) {
      int c4 = o + 8 * j;
      float4 v = *(const float4*)(rp + c4 * 4);
      ushort4 h;
      h.x = __half_as_ushort(__float2half(v.x));   // RNE
      h.y = __half_as_ushort(__float2half(v.y));
      h.z = __half_as_ushort(__float2half(v.z));
      h.w = __half_as_ushort(__float2half(v.w));
      *(ushort4*)&Xh[(size_t)row * FD + c4 * 4] = h;
      s = fmaf(v.x, v.x, s); s = fmaf(v.y, v.y, s);
      s = fmaf(v.z, v.z, s); s = fmaf(v.w, v.w, s);
    }
    s += __shfl_xor(s, 1); s += __shfl_xor(s, 2); s += __shfl_xor(s, 4);
    if (o == 0) sq[row] = s;
  }
  // zero S rows for this block (32 rows x NC floats = 8 floats/thread)
  if ((blockIdx.x + 1) * 32 <= N) {
    float4 z = {0.f, 0.f, 0.f, 0.f};
    size_t base = (size_t)blockIdx.x * 32 * NC + t * 8;
    *(float4*)&S[base] = z;
    *(float4*)&S[base + 4] = z;
  }
  if (blockIdx.x == 0 && t < out_size) out[t] = 0.f;
  // build Mt[n][col] = (labels[col]==n) ? 1.0h : 0  (8-col chunks)
  {
    int chunksPerN = N >> 3;
    int total = NC * chunksPerN;
    for (int id = blockIdx.x * 256 + t; id < total; id += gridDim.x * 256) {
      int n = id / chunksPerN;
      int c0 = (id - n * chunksPerN) * 8;
      ushort4 lo, hi;
      lo.x = (labels[c0 + 0] == n) ? 0x3C00 : 0;
      lo.y = (labels[c0 + 1] == n) ? 0x3C00 : 0;
      lo.z = (labels[c0 + 2] == n) ? 0x3C00 : 0;
      lo.w = (labels[c0 + 3] == n) ? 0x3C00 : 0;
      hi.x = (labels[c0 + 4] == n) ? 0x3C00 : 0;
      hi.y = (labels[c0 + 5] == n) ? 0x3C00 : 0;
      hi.z = (labels[c0 + 6] == n) ? 0x3C00 : 0;
      hi.w = (labels[c0 + 7] == n) ? 0x3C00 : 0;
      *(ushort4*)&Mt[(size_t)n * N + c0] = lo;
      *(ushort4*)&Mt[(size_t)n * N + c0 + 4] = hi;
    }
  }
}

// ---------------- main: fp16 MFMA Gram + MFMA segment-sum ----------------
// r7 structure, but 512 threads (8 waves, 2x4 wave grid of 64x32 tiles) and
// 2 blocks/CU -> 16 waves/CU: co-resident block fills barrier-drain stalls.
// Operand-swapped dist MFMA (transposed frags -> row-major D via ds_write_b64),
// D round-trips through Bh; one-hot M frags stream from global Mt (L2).
// NO agent-scope ops / fences anywhere (they poison the write path: r8-r10).
__global__ __launch_bounds__(512, 4)
void mfma_tile_kernel(const unsigned short* __restrict__ Xh,
                      const float* __restrict__ sq,
                      const unsigned short* __restrict__ Mt,
                      float* __restrict__ S,
                      int N, int colsPerSplit) {
  __shared__ __align__(16) unsigned short Ah[128 * LSTR];  // 34816 B
  __shared__ __align__(16) unsigned short Bh[128 * LSTR];  // 34816 B, reused as D

  const int t = threadIdx.x;
  const int R = blockIdx.x * 128;
  const int cBeg = blockIdx.y * colsPerSplit;
  const int wave = t >> 6, lane = t & 63;
  const int mm = lane & 15, quad = lane >> 4;
  const int wr = wave >> 2, wc = wave & 3;   // 2x4 wave grid: 64x32 wave tiles

  // stage A full-K: 2048 x 16B chunks over 512 threads (4 each)
  const int sr = t >> 4, sk0 = (t & 15) * 8;
#pragma unroll
  for (int it = 0; it < 4; ++it)
    *(uint4*)&Ah[(sr + it * 32) * LSTR + sk0] =
        *(const uint4*)&Xh[(size_t)(R + sr + it * 32) * FD + sk0];

  // initial B prefetch (col-tile 0) into registers
  uint4 bpref[4];
#pragma unroll
  for (int it = 0; it < 4; ++it)
    bpref[it] = *(const uint4*)&Xh[(size_t)(cBeg + sr + it * 32) * FD + sk0];

  float sqi_r[4];
#pragma unroll
  for (int ib = 0; ib < 4; ++ib)
    sqi_r[ib] = sq[R + wr * 64 + ib * 16 + mm];

  f32x4 sacc[4];                             // S accum: 16 rows/wave x 4 label-tiles
#pragma unroll
  for (int lt = 0; lt < 4; ++lt) sacc[lt] = (f32x4)0.f;

  const int numTiles = colsPerSplit / 128;
  for (int ct = 0; ct < numTiles; ++ct) {
    const int C0 = cBeg + ct * 128;
    __syncthreads();                         // prev S-pass done before Bh overwrite
#pragma unroll
    for (int it = 0; it < 4; ++it)
      *(uint4*)&Bh[(sr + it * 32) * LSTR + sk0] = bpref[it];
    const int nC0 = (ct + 1 < numTiles) ? C0 + 128 : cBeg;
#pragma unroll
    for (int it = 0; it < 4; ++it)
      bpref[it] = *(const uint4*)&Xh[(size_t)(nC0 + sr + it * 32) * FD + sk0];
    float sjr[2][4];
#pragma unroll
    for (int jb = 0; jb < 2; ++jb)
#pragma unroll
      for (int r = 0; r < 4; ++r)
        sjr[jb][r] = sq[C0 + wc * 32 + jb * 16 + quad * 4 + r];
    __syncthreads();                         // Bh ready

    // Dist pass: operands swapped -> transposed C/D fragments
    f32x4 dacc[4][2];
#pragma unroll
    for (int ib = 0; ib < 4; ++ib)
#pragma unroll
      for (int jb = 0; jb < 2; ++jb) dacc[ib][jb] = (f32x4)0.f;

#pragma unroll
    for (int ks = 0; ks < 4; ++ks) {
      const int ko = ks * 32 + quad * 8;
      f16x8 af[4], bf[2];
#pragma unroll
      for (int ib = 0; ib < 4; ++ib)
        af[ib] = *(const f16x8*)&Ah[(wr * 64 + ib * 16 + mm) * LSTR + ko];
#pragma unroll
      for (int jb = 0; jb < 2; ++jb)
        bf[jb] = *(const f16x8*)&Bh[(wc * 32 + jb * 16 + mm) * LSTR + ko];
#pragma unroll
      for (int ib = 0; ib < 4; ++ib)
#pragma unroll
        for (int jb = 0; jb < 2; ++jb)
          dacc[ib][jb] = __builtin_amdgcn_mfma_f32_16x16x32_f16(bf[jb], af[ib], dacc[ib][jb], 0, 0, 0);
    }
    __syncthreads();                         // all waves done reading Bh -> reuse as D

    // epilogue: lane holds row (lane&15), 4 contiguous cols (quad*4+r)
    const bool hasDiag = (R == C0);
#pragma unroll
    for (int ib = 0; ib < 4; ++ib) {
      const int rowLocal = wr * 64 + ib * 16 + mm;
      const float si = sqi_r[ib];
#pragma unroll
      for (int jb = 0; jb < 2; ++jb) {
        const int colBase = wc * 32 + jb * 16 + quad * 4;
        float d[4];
#pragma unroll
        for (int r = 0; r < 4; ++r) {
          float d2 = fmaf(-2.f, dacc[ib][jb][r], si + sjr[jb][r]);
          d[r] = __builtin_amdgcn_sqrtf(fmaxf(d2, 0.f));  // sqrt(0)=0: grad-safe
        }
        if (hasDiag) {
#pragma unroll
          for (int r = 0; r < 4; ++r)
            if (rowLocal == colBase + r) d[r] = 0.f;
        }
        uint2 pk;
        pk.x = __builtin_bit_cast(unsigned, __builtin_amdgcn_cvt_pkrtz(d[0], d[1]));
        pk.y = __builtin_bit_cast(unsigned, __builtin_amdgcn_cvt_pkrtz(d[2], d[3]));
        *(uint2*)&Bh[rowLocal * LSTR + colBase] = pk;    // 8B store, aligned
      }
    }
    __syncthreads();                         // D ready

    // S-pass: wave w owns rows [w*16, w*16+16); M frags direct from global Mt
    // (4 independent lt chains x 4 waves/SIMD hide the ~200cyc L2 latency)
#pragma unroll
    for (int ks = 0; ks < 4; ++ks) {
      const int ko = ks * 32 + quad * 8;
      f16x8 da = *(const f16x8*)&Bh[(wave * 16 + mm) * LSTR + ko];
#pragma unroll
      for (int lt = 0; lt < 4; ++lt) {
        f16x8 mb = *(const f16x8*)&Mt[(size_t)(lt * 16 + mm) * N + C0 + ks * 32 + quad * 8];
        sacc[lt] = __builtin_amdgcn_mfma_f32_16x16x32_f16(da, mb, sacc[lt], 0, 0, 0);
      }
    }
  }

  // flush: one plain atomicAdd per S entry (colSplit blocks contend per row)
#pragma unroll
  for (int lt = 0; lt < 4; ++lt)
#pragma unroll
    for (int r = 0; r < 4; ++r) {
      int row = wave * 16 + quad * 4 + r;
      atomicAdd(&S[(size_t)(R + row) * NC + lt * 16 + mm], sacc[lt][r]);
    }
}

// ---------------- score: hist + a/b/silhouette/mean ----------------
__global__ void score_kernel(const float* __restrict__ S,
                             const int* __restrict__ labels,
                             float* __restrict__ out, int N) {
  __shared__ int hist[NC];
  __shared__ float red[128];
  int t = threadIdx.x;
  if (t < NC) hist[t] = 0;
  __syncthreads();
  const int4* lab4 = (const int4*)labels;
  for (int i = t; i < N / 4; i += 128) {
    int4 v = lab4[i];
    atomicAdd(&hist[v.x], 1); atomicAdd(&hist[v.y], 1);
    atomicAdd(&hist[v.z], 1); atomicAdd(&hist[v.w], 1);
  }
  __syncthreads();
  int i = blockIdx.x * 128 + t;
  float score = 0.f;
  if (i < N) {
    int li = labels[i];
    float own = (float)hist[li];
    float a = 0.f, b = FLT_MAX;
    const float* Si = S + (size_t)i * NC;
#pragma unroll
    for (int c = 0; c < NC; ++c) {
      float s = Si[c];
      float cf = (float)hist[c];
      if (c == li) a = s / fmaxf(own - 1.f, 1.f);
      else if (cf != 0.f) b = fminf(b, s / cf);
    }
    float mx = fmaxf(a, b);
    score = (own > 1.f) ? (b - a) / mx : 0.f;
  }
  red[t] = score;
  __syncthreads();
  for (int sft = 64; sft > 0; sft >>= 1) {
    if (t < sft) red[t] += red[t + sft];
    __syncthreads();
  }
  if (t == 0) atomicAdd(out, red[0] / (float)N);
}

extern "C" void kernel_launch(void* const* d_in, const int* in_sizes, int n_in,
                              void* d_out, int out_size, void* d_ws, size_t ws_size,
                              hipStream_t stream) {
  const float* feat = (const float*)d_in[0];
  const int* labels = (const int*)d_in[1];
  const int N = in_sizes[1];            // 8192; D=128, C=64 fixed by the reference
  float* out = (float*)d_out;
  char* ws = (char*)d_ws;

  // ws: sq(N*4) | Xh(N*128*2) | Mt(64*N*2) | S(N*64*4)  ~5.03 MB @8192
  float* sq = (float*)ws;
  size_t o = ((size_t)N * 4 + 255) & ~(size_t)255;
  unsigned short* Xh = (unsigned short*)(ws + o);                       // N*FD*2
  unsigned short* Mt = (unsigned short*)(ws + o + (size_t)N * FD * 2);  // NC*N*2
  float* S = (float*)(ws + o + (size_t)N * FD * 2 + (size_t)NC * N * 2);

  prep_kernel<<<(N + 31) / 32, 256, 0, stream>>>(feat, labels, sq, Xh, Mt, S,
                                                 out, out_size, N);

  const int colSplit = 8;               // 64 x 8 = 512 blocks = 2/CU (8 waves each)
  dim3 grid(N / 128, colSplit);
  mfma_tile_kernel<<<grid, 512, 0, stream>>>(Xh, sq, Mt, S, N, N / colSplit);

  score_kernel<<<(N + 127) / 128, 128, 0, stream>>>(S, labels, out, N);
}

// Round 12
// 159.400 us; speedup vs baseline: 1.4079x; 1.1057x over previous
//
#include <hip/hip_runtime.h>
#include <hip/hip_fp16.h>
#include <float.h>

#define NC 64     // clusters
#define FD 128    // feature dim
#define LSTR 136  // LDS row stride in halfs (pad 16B; frag-read conflicts 2-way = free)

typedef _Float16 f16x8 __attribute__((ext_vector_type(8)));
typedef float f32x4 __attribute__((ext_vector_type(4)));

// ---------------- prep: fp16 cast, |x|^2, Mt build, S/out zero ----------------
__global__ void prep_kernel(const float* __restrict__ feat,
                            const int* __restrict__ labels,
                            float* __restrict__ sq,
                            unsigned short* __restrict__ Xh,
                            unsigned short* __restrict__ Mt,
                            float* __restrict__ S,
                            float* __restrict__ out, int out_size, int N) {
  int t = threadIdx.x;
  int row = blockIdx.x * 32 + (t >> 3);
  int o = t & 7;
  if (row < N) {
    const float* rp = feat + (size_t)row * FD;
    float s = 0.f;
#pragma unroll
    for (int j = 0; j < 4; ++j) {
      int c4 = o + 8 * j;
      float4 v = *(const float4*)(rp + c4 * 4);
      ushort4 h;
      h.x = __half_as_ushort(__float2half(v.x));   // RNE
      h.y = __half_as_ushort(__float2half(v.y));
      h.z = __half_as_ushort(__float2half(v.z));
      h.w = __half_as_ushort(__float2half(v.w));
      *(ushort4*)&Xh[(size_t)row * FD + c4 * 4] = h;
      s = fmaf(v.x, v.x, s); s = fmaf(v.y, v.y, s);
      s = fmaf(v.z, v.z, s); s = fmaf(v.w, v.w, s);
    }
    s += __shfl_xor(s, 1); s += __shfl_xor(s, 2); s += __shfl_xor(s, 4);
    if (o == 0) sq[row] = s;
  }
  // zero S rows for this block (32 rows x NC floats = 8 floats/thread)
  if ((blockIdx.x + 1) * 32 <= N) {
    float4 z = {0.f, 0.f, 0.f, 0.f};
    size_t base = (size_t)blockIdx.x * 32 * NC + t * 8;
    *(float4*)&S[base] = z;
    *(float4*)&S[base + 4] = z;
  }
  if (blockIdx.x == 0 && t < out_size) out[t] = 0.f;
  // build Mt[n][col] = (labels[col]==n) ? 1.0h : 0  (8-col chunks)
  {
    int chunksPerN = N >> 3;
    int total = NC * chunksPerN;
    for (int id = blockIdx.x * 256 + t; id < total; id += gridDim.x * 256) {
      int n = id / chunksPerN;
      int c0 = (id - n * chunksPerN) * 8;
      ushort4 lo, hi;
      lo.x = (labels[c0 + 0] == n) ? 0x3C00 : 0;
      lo.y = (labels[c0 + 1] == n) ? 0x3C00 : 0;
      lo.z = (labels[c0 + 2] == n) ? 0x3C00 : 0;
      lo.w = (labels[c0 + 3] == n) ? 0x3C00 : 0;
      hi.x = (labels[c0 + 4] == n) ? 0x3C00 : 0;
      hi.y = (labels[c0 + 5] == n) ? 0x3C00 : 0;
      hi.z = (labels[c0 + 6] == n) ? 0x3C00 : 0;
      hi.w = (labels[c0 + 7] == n) ? 0x3C00 : 0;
      *(ushort4*)&Mt[(size_t)n * N + c0] = lo;
      *(ushort4*)&Mt[(size_t)n * N + c0 + 4] = hi;
    }
  }
}

// ---------------- main: fp16 MFMA Gram + MFMA segment-sum ----------------
// 512 threads (8 waves, 2x4 wave grid of 64x32 tiles), 2 blocks/CU -> 16 waves/CU.
// NO register prefetch: r8-r11 showed the allocator spills any value held live
// across the col-tile body, and the scratch spill/fill traffic (~100+ MB of HBM
// writes via L2 eviction) dwarfs any prefetch benefit. Staging is load->LDS
// directly (r7 style, instantaneous liveness).
__global__ __launch_bounds__(512, 4)
void mfma_tile_kernel(const unsigned short* __restrict__ Xh,
                      const float* __restrict__ sq,
                      const unsigned short* __restrict__ Mt,
                      float* __restrict__ S,
                      int N, int colsPerSplit) {
  __shared__ __align__(16) unsigned short Ah[128 * LSTR];  // 34816 B
  __shared__ __align__(16) unsigned short Bh[128 * LSTR];  // 34816 B, reused as D

  const int t = threadIdx.x;
  const int R = blockIdx.x * 128;
  const int cBeg = blockIdx.y * colsPerSplit;
  const int wave = t >> 6, lane = t & 63;
  const int mm = lane & 15, quad = lane >> 4;
  const int wr = wave >> 2, wc = wave & 3;   // 2x4 wave grid: 64x32 wave tiles

  // stage A full-K: 2048 x 16B chunks over 512 threads (4 each)
  const int sr = t >> 4, sk0 = (t & 15) * 8;
#pragma unroll
  for (int it = 0; it < 4; ++it)
    *(uint4*)&Ah[(sr + it * 32) * LSTR + sk0] =
        *(const uint4*)&Xh[(size_t)(R + sr + it * 32) * FD + sk0];

  float sqi_r[4];
#pragma unroll
  for (int ib = 0; ib < 4; ++ib)
    sqi_r[ib] = sq[R + wr * 64 + ib * 16 + mm];

  f32x4 sacc[4];                             // S accum: 16 rows/wave x 4 label-tiles
#pragma unroll
  for (int lt = 0; lt < 4; ++lt) sacc[lt] = (f32x4)0.f;

  const int numTiles = colsPerSplit / 128;
  for (int ct = 0; ct < numTiles; ++ct) {
    const int C0 = cBeg + ct * 128;
    __syncthreads();                         // prev S-pass done before Bh overwrite
#pragma unroll
    for (int it = 0; it < 4; ++it)
      *(uint4*)&Bh[(sr + it * 32) * LSTR + sk0] =
          *(const uint4*)&Xh[(size_t)(C0 + sr + it * 32) * FD + sk0];
    float sjr[2][4];
#pragma unroll
    for (int jb = 0; jb < 2; ++jb)
#pragma unroll
      for (int r = 0; r < 4; ++r)
        sjr[jb][r] = sq[C0 + wc * 32 + jb * 16 + quad * 4 + r];
    __syncthreads();                         // Bh ready

    // Dist pass: operands swapped -> transposed C/D fragments
    f32x4 dacc[4][2];
#pragma unroll
    for (int ib = 0; ib < 4; ++ib)
#pragma unroll
      for (int jb = 0; jb < 2; ++jb) dacc[ib][jb] = (f32x4)0.f;

#pragma unroll
    for (int ks = 0; ks < 4; ++ks) {
      const int ko = ks * 32 + quad * 8;
      f16x8 af[4], bf[2];
#pragma unroll
      for (int ib = 0; ib < 4; ++ib)
        af[ib] = *(const f16x8*)&Ah[(wr * 64 + ib * 16 + mm) * LSTR + ko];
#pragma unroll
      for (int jb = 0; jb < 2; ++jb)
        bf[jb] = *(const f16x8*)&Bh[(wc * 32 + jb * 16 + mm) * LSTR + ko];
#pragma unroll
      for (int ib = 0; ib < 4; ++ib)
#pragma unroll
        for (int jb = 0; jb < 2; ++jb)
          dacc[ib][jb] = __builtin_amdgcn_mfma_f32_16x16x32_f16(bf[jb], af[ib], dacc[ib][jb], 0, 0, 0);
    }
    __syncthreads();                         // all waves done reading Bh -> reuse as D

    // epilogue: lane holds row (lane&15), 4 contiguous cols (quad*4+r)
    const bool hasDiag = (R == C0);
#pragma unroll
    for (int ib = 0; ib < 4; ++ib) {
      const int rowLocal = wr * 64 + ib * 16 + mm;
      const float si = sqi_r[ib];
#pragma unroll
      for (int jb = 0; jb < 2; ++jb) {
        const int colBase = wc * 32 + jb * 16 + quad * 4;
        float d[4];
#pragma unroll
        for (int r = 0; r < 4; ++r) {
          float d2 = fmaf(-2.f, dacc[ib][jb][r], si + sjr[jb][r]);
          d[r] = __builtin_amdgcn_sqrtf(fmaxf(d2, 0.f));  // sqrt(0)=0: grad-safe
        }
        if (hasDiag) {
#pragma unroll
          for (int r = 0; r < 4; ++r)
            if (rowLocal == colBase + r) d[r] = 0.f;
        }
        uint2 pk;
        pk.x = __builtin_bit_cast(unsigned, __builtin_amdgcn_cvt_pkrtz(d[0], d[1]));
        pk.y = __builtin_bit_cast(unsigned, __builtin_amdgcn_cvt_pkrtz(d[2], d[3]));
        *(uint2*)&Bh[rowLocal * LSTR + colBase] = pk;    // 8B store, aligned
      }
    }
    __syncthreads();                         // D ready

    // S-pass: wave w owns rows [w*16, w*16+16); M frags direct from global Mt
#pragma unroll
    for (int ks = 0; ks < 4; ++ks) {
      const int ko = ks * 32 + quad * 8;
      f16x8 da = *(const f16x8*)&Bh[(wave * 16 + mm) * LSTR + ko];
#pragma unroll
      for (int lt = 0; lt < 4; ++lt) {
        f16x8 mb = *(const f16x8*)&Mt[(size_t)(lt * 16 + mm) * N + C0 + ks * 32 + quad * 8];
        sacc[lt] = __builtin_amdgcn_mfma_f32_16x16x32_f16(da, mb, sacc[lt], 0, 0, 0);
      }
    }
  }

  // flush: one plain atomicAdd per S entry (colSplit blocks contend per row)
#pragma unroll
  for (int lt = 0; lt < 4; ++lt)
#pragma unroll
    for (int r = 0; r < 4; ++r) {
      int row = wave * 16 + quad * 4 + r;
      atomicAdd(&S[(size_t)(R + row) * NC + lt * 16 + mm], sacc[lt][r]);
    }
}

// ---------------- score: hist + a/b/silhouette/mean ----------------
__global__ void score_kernel(const float* __restrict__ S,
                             const int* __restrict__ labels,
                             float* __restrict__ out, int N) {
  __shared__ int hist[NC];
  __shared__ float red[128];
  int t = threadIdx.x;
  if (t < NC) hist[t] = 0;
  __syncthreads();
  const int4* lab4 = (const int4*)labels;
  for (int i = t; i < N / 4; i += 128) {
    int4 v = lab4[i];
    atomicAdd(&hist[v.x], 1); atomicAdd(&hist[v.y], 1);
    atomicAdd(&hist[v.z], 1); atomicAdd(&hist[v.w], 1);
  }
  __syncthreads();
  int i = blockIdx.x * 128 + t;
  float score = 0.f;
  if (i < N) {
    int li = labels[i];
    float own = (float)hist[li];
    float a = 0.f, b = FLT_MAX;
    const float* Si = S + (size_t)i * NC;
#pragma unroll
    for (int c = 0; c < NC; ++c) {
      float s = Si[c];
      float cf = (float)hist[c];
      if (c == li) a = s / fmaxf(own - 1.f, 1.f);
      else if (cf != 0.f) b = fminf(b, s / cf);
    }
    float mx = fmaxf(a, b);
    score = (own > 1.f) ? (b - a) / mx : 0.f;
  }
  red[t] = score;
  __syncthreads();
  for (int sft = 64; sft > 0; sft >>= 1) {
    if (t < sft) red[t] += red[t + sft];
    __syncthreads();
  }
  if (t == 0) atomicAdd(out, red[0] / (float)N);
}

extern "C" void kernel_launch(void* const* d_in, const int* in_sizes, int n_in,
                              void* d_out, int out_size, void* d_ws, size_t ws_size,
                              hipStream_t stream) {
  const float* feat = (const float*)d_in[0];
  const int* labels = (const int*)d_in[1];
  const int N = in_sizes[1];            // 8192; D=128, C=64 fixed by the reference
  float* out = (float*)d_out;
  char* ws = (char*)d_ws;

  // ws: sq(N*4) | Xh(N*128*2) | Mt(64*N*2) | S(N*64*4)  ~5.03 MB @8192
  float* sq = (float*)ws;
  size_t o = ((size_t)N * 4 + 255) & ~(size_t)255;
  unsigned short* Xh = (unsigned short*)(ws + o);                       // N*FD*2
  unsigned short* Mt = (unsigned short*)(ws + o + (size_t)N * FD * 2);  // NC*N*2
  float* S = (float*)(ws + o + (size_t)N * FD * 2 + (size_t)NC * N * 2);

  prep_kernel<<<(N + 31) / 32, 256, 0, stream>>>(feat, labels, sq, Xh, Mt, S,
                                                 out, out_size, N);

  const int colSplit = 8;               // 64 x 8 = 512 blocks = 2/CU (8 waves each)
  dim3 grid(N / 128, colSplit);
  mfma_tile_kernel<<<grid, 512, 0, stream>>>(Xh, sq, Mt, S, N, N / colSplit);

  score_kernel<<<(N + 127) / 128, 128, 0, stream>>>(S, labels, out, N);
}